// Round 2
// baseline (718.080 us; speedup 1.0000x reference)
//
#include <hip/hip_runtime.h>
#include <hip/hip_bf16.h>

#define NB 2048      // batches
#define NP 32        // particles per batch
#define ND 6         // action dim
#define NOBS 17      // obs dim
#define NH 256       // hidden
#define NSTEPS 10
#define C_LR 0.1f
#define C_LIM 1.0f
#define C_LOGNP1 3.4965075614664802f   // float32(log(33))

typedef __bf16 bf16x8 __attribute__((ext_vector_type(8)));
typedef float  f32x4  __attribute__((ext_vector_type(4)));
typedef float  f32x2  __attribute__((ext_vector_type(2)));

#define MFMA(a, b, c) __builtin_amdgcn_mfma_f32_16x16x32_bf16(a, b, c, 0, 0, 0)

// fp32 -> bf16 bits, round-to-nearest-even (finite inputs)
static __device__ __forceinline__ unsigned short f2bf(float f) {
    union { float f; unsigned u; } c; c.f = f;
    const unsigned r = c.u + 0x7fffu + ((c.u >> 16) & 1u);
    return (unsigned short)(r >> 16);
}

// packed fp32x2 -> bf16x2 (RNE), 1 VALU op for 2 conversions
static __device__ __forceinline__ unsigned cvtpk_bf16(float lo, float hi) {
    unsigned r;
    asm("v_cvt_pk_bf16_f32 %0, %1, %2" : "=v"(r) : "v"(lo), "v"(hi));
    return r;
}

// A/C column n -> u16 offset base (bits 0-2: n&7, 7-8: (n>>3)&3, 11+: n>>5)
static __device__ __forceinline__ int colpf(int n) {
    return ((n >> 5) << 11) + (((n >> 3) & 3) << 7) + (n & 7);
}

// Xs/sc_ row swizzle: element (p,d) lives at float idx (p*8 + d) ^ XSW(p).
// Spreads the 4 jgo-groups (p stride 8) across 4 distinct bank quads.
#define XSW(p) ((((p) >> 3) & 3) << 3)

// ---------------------------------------------------------------------------
// Prep: B-fragment-swizzled bf16 copies in d_ws (unchanged).
//   ws[0      ..65535]  : W2    as B (fwd)
//   ws[65536  ..131071] : W2^T  as B (bwd)
//   ws[131072 ..135167] : W1x^T (256x16, cols>=6 zero) as B (score GEMM)
//   ws[135168 ..143359] : W1aug (32x256: rows 0..22 = W1, 23..31 = 0) as B
// ---------------------------------------------------------------------------
__global__ void prep_swizzle(const float* __restrict__ W1, const float* __restrict__ W2,
                             unsigned short* __restrict__ ws) {
    const int g = blockIdx.x * 256 + threadIdx.x;
    unsigned short v[8];
    if (g < 8192) {
        const int l = g & 63, fid = g >> 6;
        const int kt = fid >> 4, nt = fid & 15;
        const int row0 = kt * 32 + (l >> 4) * 8;
        const int col  = nt * 16 + (l & 15);
#pragma unroll
        for (int j = 0; j < 8; ++j) v[j] = f2bf(W2[(row0 + j) * NH + col]);
        ushort4* dst = (ushort4*)(ws + (size_t)g * 8);
        dst[0] = make_ushort4(v[0], v[1], v[2], v[3]);
        dst[1] = make_ushort4(v[4], v[5], v[6], v[7]);
    } else if (g < 16384) {
        const int e = g - 8192;
        const int l = e & 63, fid = e >> 6;
        const int kt = fid >> 4, nt = fid & 15;
        const int row  = nt * 16 + (l & 15);        // W2^T[k][n] = W2[n][k]
        const int col0 = kt * 32 + (l >> 4) * 8;
#pragma unroll
        for (int j = 0; j < 8; ++j) v[j] = f2bf(W2[row * NH + col0 + j]);
        ushort4* dst = (ushort4*)(ws + 65536 + (size_t)e * 8);
        dst[0] = make_ushort4(v[0], v[1], v[2], v[3]);
        dst[1] = make_ushort4(v[4], v[5], v[6], v[7]);
    } else if (g < 16896) {
        const int e = g - 16384;
        const int l = e & 63, kt = e >> 6;
        const int n  = l & 15;
        const int k0 = kt * 32 + (l >> 4) * 8;
#pragma unroll
        for (int j = 0; j < 8; ++j)
            v[j] = (n < ND) ? f2bf(W1[(NOBS + n) * NH + k0 + j]) : (unsigned short)0;
        ushort4* dst = (ushort4*)(ws + 131072 + (size_t)e * 8);
        dst[0] = make_ushort4(v[0], v[1], v[2], v[3]);
        dst[1] = make_ushort4(v[4], v[5], v[6], v[7]);
    } else if (g < 17920) {
        const int e = g - 16896;                    // 16 frags (nt) x 64 lanes
        const int l = e & 63, nt = e >> 6;
        const int col = nt * 16 + (l & 15);
        const int r0  = (l >> 4) * 8;
#pragma unroll
        for (int j = 0; j < 8; ++j)
            v[j] = (r0 + j < NOBS + ND) ? f2bf(W1[(r0 + j) * NH + col]) : (unsigned short)0;
        ushort4* dst = (ushort4*)(ws + 135168 + (size_t)e * 8);
        dst[0] = make_ushort4(v[0], v[1], v[2], v[3]);
        dst[1] = make_ushort4(v[4], v[5], v[6], v[7]);
    }
}

// ---------------------------------------------------------------------------
// Main kernel: one WG per TWO batches (M=64 GEMMs), 256 threads = 4 waves.
// hA layout v2 for 64x256 matrix M[s][c] (u16 addr bits):
//   b0-2 = c&7 | b3-4 = (s>>2)&3 | b5-6 = (s&3), b5 ^= (c>>3)&1 | b7-8 = (c>>3)&3
//   b9-10 = s>>4 | b11+ = c>>5
// Epilogue b16 writes: 2-way banked (was 8-way). ds_read_b128 reads stay
// conflict-free via per-thread base lb (element-verified vs write side).
// ---------------------------------------------------------------------------
__global__ __launch_bounds__(256, 4)
void svgd_kernel(const float* __restrict__ obs, const float* __restrict__ a_in,
                 const float* __restrict__ W1, const float* __restrict__ b1,
                 const float* __restrict__ W2, const float* __restrict__ b2,
                 const float* __restrict__ W3, const unsigned short* __restrict__ ws,
                 float* __restrict__ out)
{
    __shared__ __attribute__((aligned(16))) unsigned short hA[64 * NH]; // 32KB h1 -> dh2 -> masked dh1
    __shared__ __attribute__((aligned(16))) float Xs[2][512];  // 4KB dbuf X, stride 8, XSW-swizzled
    __shared__ __attribute__((aligned(16))) float sc_[512];    // 2KB score, stride 8, XSW-swizzled
    __shared__ float med_s[2];
    // total ~38.9KB -> 4 WGs/CU

    const int t    = threadIdx.x;
    const int bb   = blockIdx.x;        // batches 2bb, 2bb+1
    const int lane = t & 63;
    const int wid  = t >> 6;
    const int w4   = wid * 4;           // this wave's first nt (GEMM N-split)
    const int quad = lane >> 4;
    const int ln15 = lane & 15;
    const int qo = t >> 7, iao = (t & 127) >> 2, jgo = t & 3;

    // swizzled hA fragment-read base (replaces lane*8); per-thread constant
    const int lb = (((lane >> 2) & 3) << 3)
                 | (((lane & 3) ^ ((lane >> 4) & 1)) << 5)
                 | ((lane >> 4) << 7);
    // write-side bit5 swizzle mask: ((n>>3)&1)<<5 == ((ln15>>3)&1)<<5 (q-invariant)
    const int x5t = ((ln15 >> 3) & 1) << 5;

    const unsigned short* gW2f = ws;
    const unsigned short* gW2b = ws + 65536;
    const unsigned short* gW1p = ws + 131072;
    const unsigned short* gW1f = ws + 135168;

    // ---- init: obs -> hA scratch (coalesced), X -> Xs[0] (restrided+swizzled) ----
    {
        float* scr = (float*)hA;
        const float* obs_g = obs + (size_t)bb * 1088;
        for (int p = t; p < 1088; p += 256) scr[p] = obs_g[p];
        const float* a_g = a_in + (size_t)bb * 384;
        for (int e = t; e < 384; e += 256) {
            const int p = e / 6, d = e - p * 6;
            Xs[0][((p * 8) ^ XSW(p)) + d] = a_g[e];
        }
    }
    __syncthreads();
    // a0: A-fragments of [obs|X|0] (64 rows x K=32) in registers, all 4 waves
    bf16x8 a0[4];
    {
        const float* scr = (const float*)hA;
#pragma unroll
        for (int m = 0; m < 4; ++m) {
            const int s = m * 16 + ln15;
#pragma unroll
            for (int j = 0; j < 8; ++j) {
                const int k = quad * 8 + j;
                float v = 0.0f;
                if (k < NOBS) v = scr[s * NOBS + k];
                else if (k < NOBS + ND) v = Xs[0][((s * 8) ^ XSW(s)) + (k - NOBS)];
                a0[m][j] = (__bf16)v;
            }
        }
    }
    __syncthreads();   // scr reads done before step-0 P0 writes hA

    // ---- persistent per-thread scalars ----
    float b1r[4], b2r[4]; unsigned short w3u[4];
#pragma unroll
    for (int q = 0; q < 4; ++q) {
        const int n = (w4 + q) * 16 + ln15;
        b1r[q] = b1[n]; b2r[q] = b2[n]; w3u[q] = f2bf(W3[n]);
    }

    float logp_r = 0.0f;                // owned by jgo==3 threads
    int cur = 0;
    const f32x4 zv = {0.f, 0.f, 0.f, 0.f};

    for (int step = 0; step < NSTEPS; ++step) {
        // ---- P0: h1 = relu([obs|X] @ W1aug + b1), single pass, mask1 saved ----
        unsigned long long mask1 = 0ull;
        {
            bf16x8 w1B[4];
#pragma unroll
            for (int q = 0; q < 4; ++q)
                w1B[q] = *(const bf16x8*)(gW1f + ((w4 + q) * 64 + lane) * 8);
            f32x4 acc0[4][4];
#pragma unroll
            for (int m = 0; m < 4; ++m)
#pragma unroll
                for (int q = 0; q < 4; ++q) acc0[m][q] = MFMA(a0[m], w1B[q], zv);
#pragma unroll
            for (int q = 0; q < 4; ++q) {
                const int cq = colpf((w4 + q) * 16 + ln15) + quad * 8;
                const int ax0 = (cq     ) ^ x5t;
                const int ax1 = (cq + 32) ^ x5t;
                const int ax2 = (cq + 64) ^ x5t;
                const int ax3 = (cq + 96) ^ x5t;
                const float b1v = b1r[q];
#pragma unroll
                for (int m = 0; m < 4; ++m) {
                    const float f0 = acc0[m][q][0] + b1v;
                    const float f1 = acc0[m][q][1] + b1v;
                    const float f2 = acc0[m][q][2] + b1v;
                    const float f3 = acc0[m][q][3] + b1v;
                    if (f0 > 0.f) mask1 |= 1ull << (q * 16 + m * 4 + 0);
                    if (f1 > 0.f) mask1 |= 1ull << (q * 16 + m * 4 + 1);
                    if (f2 > 0.f) mask1 |= 1ull << (q * 16 + m * 4 + 2);
                    if (f3 > 0.f) mask1 |= 1ull << (q * 16 + m * 4 + 3);
                    const unsigned pk01 = cvtpk_bf16(fmaxf(f0, 0.f), fmaxf(f1, 0.f));
                    const unsigned pk23 = cvtpk_bf16(fmaxf(f2, 0.f), fmaxf(f3, 0.f));
                    hA[ax0 + m * 512] = (unsigned short)pk01;
                    hA[ax1 + m * 512] = (unsigned short)(pk01 >> 16);
                    hA[ax2 + m * 512] = (unsigned short)pk23;
                    hA[ax3 + m * 512] = (unsigned short)(pk23 >> 16);
                }
            }
        }
        __syncthreads();  // S1

        // ---- P2: fwd GEMM h2_pre = h1 @ W2, single pass ----
        {
            f32x4 acc[4][4];
#pragma unroll
            for (int m = 0; m < 4; ++m)
#pragma unroll
                for (int q = 0; q < 4; ++q) acc[m][q] = zv;
#pragma unroll 2
            for (int kt = 0; kt < 8; ++kt) {
                bf16x8 a[4];
#pragma unroll
                for (int m = 0; m < 4; ++m)
                    a[m] = *(const bf16x8*)&hA[(kt * 4 + m) * 512 + lb];
#pragma unroll
                for (int q = 0; q < 4; ++q) {
                    const bf16x8 bf = *(const bf16x8*)(gW2f + ((kt * 16 + w4 + q) * 64 + lane) * 8);
#pragma unroll
                    for (int m = 0; m < 4; ++m) acc[m][q] = MFMA(a[m], bf, acc[m][q]);
                }
            }
            __syncthreads();  // S2: all h1 reads done
            // epilogue: dh2 = (h2_pre + b2 > 0) ? W3 : 0, straight from acc
#pragma unroll
            for (int q = 0; q < 4; ++q) {
                const int cq = colpf((w4 + q) * 16 + ln15) + quad * 8;
                const int ax0 = (cq     ) ^ x5t;
                const int ax1 = (cq + 32) ^ x5t;
                const int ax2 = (cq + 64) ^ x5t;
                const int ax3 = (cq + 96) ^ x5t;
                const float b2v = b2r[q];
                const unsigned short w3v = w3u[q];
#pragma unroll
                for (int m = 0; m < 4; ++m) {
                    hA[ax0 + m * 512] = (acc[m][q][0] + b2v > 0.f) ? w3v : (unsigned short)0;
                    hA[ax1 + m * 512] = (acc[m][q][1] + b2v > 0.f) ? w3v : (unsigned short)0;
                    hA[ax2 + m * 512] = (acc[m][q][2] + b2v > 0.f) ? w3v : (unsigned short)0;
                    hA[ax3 + m * 512] = (acc[m][q][3] + b2v > 0.f) ? w3v : (unsigned short)0;
                }
            }
        }
        __syncthreads();  // S3: dh2 visible

        // ---- P3: bwd GEMM dh1 = dh2 @ W2^T, single pass ----
        {
            f32x4 acc2[4][4];
#pragma unroll
            for (int m = 0; m < 4; ++m)
#pragma unroll
                for (int q = 0; q < 4; ++q) acc2[m][q] = zv;
#pragma unroll 2
            for (int kt = 0; kt < 8; ++kt) {
                bf16x8 a[4];
#pragma unroll
                for (int m = 0; m < 4; ++m)
                    a[m] = *(const bf16x8*)&hA[(kt * 4 + m) * 512 + lb];
#pragma unroll
                for (int q = 0; q < 4; ++q) {
                    const bf16x8 bf = *(const bf16x8*)(gW2b + ((kt * 16 + w4 + q) * 64 + lane) * 8);
#pragma unroll
                    for (int m = 0; m < 4; ++m) acc2[m][q] = MFMA(a[m], bf, acc2[m][q]);
                }
            }
            __syncthreads();  // S4: all dh2 reads done
            // epilogue: masked dh1 from register bitmask
#pragma unroll
            for (int q = 0; q < 4; ++q) {
                const int cq = colpf((w4 + q) * 16 + ln15) + quad * 8;
                const int ax0 = (cq     ) ^ x5t;
                const int ax1 = (cq + 32) ^ x5t;
                const int ax2 = (cq + 64) ^ x5t;
                const int ax3 = (cq + 96) ^ x5t;
#pragma unroll
                for (int m = 0; m < 4; ++m) {
                    const int kb = q * 16 + m * 4;
                    const float v0 = ((mask1 >> (kb + 0)) & 1ull) ? acc2[m][q][0] : 0.f;
                    const float v1 = ((mask1 >> (kb + 1)) & 1ull) ? acc2[m][q][1] : 0.f;
                    const float v2 = ((mask1 >> (kb + 2)) & 1ull) ? acc2[m][q][2] : 0.f;
                    const float v3 = ((mask1 >> (kb + 3)) & 1ull) ? acc2[m][q][3] : 0.f;
                    const unsigned pk01 = cvtpk_bf16(v0, v1);
                    const unsigned pk23 = cvtpk_bf16(v2, v3);
                    hA[ax0 + m * 512] = (unsigned short)pk01;
                    hA[ax1 + m * 512] = (unsigned short)(pk01 >> 16);
                    hA[ax2 + m * 512] = (unsigned short)pk23;
                    hA[ax3 + m * 512] = (unsigned short)(pk23 >> 16);
                }
            }
        }
        __syncthreads();  // S5: masked dh1 visible

        // ---- P5: waves 2,3: score GEMM; waves 0,1: exact median ----
        if (wid >= 2) {
            const int mb = (wid - 2) * 2;
            f32x4 sa[2] = {zv, zv};
#pragma unroll
            for (int kt = 0; kt < 8; ++kt) {
                const bf16x8 bw = *(const bf16x8*)(gW1p + (kt * 64 + lane) * 8);
#pragma unroll
                for (int mm = 0; mm < 2; ++mm) {
                    const bf16x8 a = *(const bf16x8*)&hA[(kt * 4 + mb + mm) * 512 + lb];
                    sa[mm] = MFMA(a, bw, sa[mm]);
                }
            }
            if (ln15 < ND) {
#pragma unroll
                for (int mm = 0; mm < 2; ++mm)
#pragma unroll
                    for (int reg = 0; reg < 4; ++reg) {
                        const int row = (mb + mm) * 16 + quad * 4 + reg;
                        sc_[((row * 8) ^ XSW(row)) + ln15] = sa[mm][reg];
                    }
            }
        } else {
            // rank-239 of 496 pair dists == rank-511 of full 1024 multiset.
            // Bits 30..8 suffice: med rel-err < 2^-15, invisible vs bf16 noise.
            const float* Xc = &Xs[cur][wid * 256];
            unsigned u[8];
#pragma unroll
            for (int r = 0; r < 8; ++r) {
                const int e = lane + 64 * r;
                if (e < 496) {
                    int i = (int)((63.0f - sqrtf(3969.0f - 8.0f * (float)e)) * 0.5f);
                    while (i * (63 - i) / 2 > e) --i;
                    while ((i + 1) * (62 - i) / 2 <= e) ++i;
                    const int j = i + 1 + (e - i * (63 - i) / 2);
                    const int ibz = (i * 8) ^ XSW(i), jbz = (j * 8) ^ XSW(j);
                    const f32x4 pa = *(const f32x4*)&Xc[ibz];
                    const f32x2 pb = *(const f32x2*)&Xc[ibz + 4];
                    const f32x4 qa = *(const f32x4*)&Xc[jbz];
                    const f32x2 qb = *(const f32x2*)&Xc[jbz + 4];
                    float s = 0.f;
                    {
                        float df;
                        df = pa[0] - qa[0]; s += df * df;
                        df = pa[1] - qa[1]; s += df * df;
                        df = pa[2] - qa[2]; s += df * df;
                        df = pa[3] - qa[3]; s += df * df;
                        df = pb[0] - qb[0]; s += df * df;
                        df = pb[1] - qb[1]; s += df * df;
                    }
                    u[r] = __float_as_uint(s);
                } else u[r] = 0x7f800000u;
            }
            unsigned P = 0u;
            for (int bit = 30; bit >= 8; --bit) {
                const unsigned Q = P | (1u << bit);
                int c = 0;
#pragma unroll
                for (int r = 0; r < 8; ++r)
                    c += __popcll(__ballot(u[r] < Q));
                if (c <= 239) P = Q;
            }
            if (lane == 0) med_s[wid] = __uint_as_float(P);
        }
        __syncthreads();  // S6

        // ---- phi/l4/l5 partials; thread (batch qo, particle iao, 8 j's) ----
        {
            const int nxt = cur ^ 1;
            const float gam = 1.0f / (1e-8f + med_s[qo] / C_LOGNP1);
            const float* Xc = &Xs[cur][qo * 256];
            const int xib = (iao * 8) ^ XSW(iao);
            const f32x4 xa = *(const f32x4*)&Xc[xib];
            const f32x2 xb = *(const f32x2*)&Xc[xib + 4];
            float xi[6] = {xa[0], xa[1], xa[2], xa[3], xb[0], xb[1]};
            float w[8] = {0, 0, 0, 0, 0, 0, 0, 0};
#pragma unroll
            for (int jj = 0; jj < 8; ++jj) {
                const int j = jgo * 8 + jj;
                const int jb = (j * 8) ^ XSW(j);
                const f32x4 qa  = *(const f32x4*)&Xc[jb];
                const f32x2 qb  = *(const f32x2*)&Xc[jb + 4];
                const f32x4 sa4 = *(const f32x4*)&sc_[qo * 256 + jb];
                const f32x2 sb2 = *(const f32x2*)&sc_[qo * 256 + jb + 4];
                const float df6[6] = {xi[0] - qa[0], xi[1] - qa[1], xi[2] - qa[2],
                                      xi[3] - qa[3], xi[4] - qb[0], xi[5] - qb[1]};
                const float sj6[6] = {sa4[0], sa4[1], sa4[2], sa4[3], sb2[0], sb2[1]};
                float dsv = 0.f, dot = 0.f;
#pragma unroll
                for (int d = 0; d < ND; ++d) {
                    dsv += df6[d] * df6[d];
                    dot += df6[d] * sj6[d];
                }
                const float kap = __expf(-gam * dsv);
                const float tg = 2.0f * gam * kap;
#pragma unroll
                for (int d = 0; d < ND; ++d) w[d] += kap * sj6[d] + tg * df6[d];
                w[6] -= tg * dot;                 // line_4 partial
                w[7] += tg * dsv - 6.0f * kap;    // line_5 partial (pre -2*gamma)
            }
#pragma unroll
            for (int off = 1; off < 4; off <<= 1)
#pragma unroll
                for (int c = 0; c < 8; ++c) w[c] += __shfl_xor(w[c], off);
            // commit to Xs[nxt] (disjoint buffer: no barrier vs phi reads)
            const int wb = qo * 256 + xib;
            {
                float x = xi[jgo] + C_LR * (w[jgo] * (1.0f / 32.0f));
                Xs[nxt][wb + jgo] = fminf(fmaxf(x, -C_LIM), C_LIM);
            }
            if (jgo < 2) {
                const int d = jgo + 4;
                float x = xi[d] + C_LR * (w[d] * (1.0f / 32.0f));
                Xs[nxt][wb + d] = fminf(fmaxf(x, -C_LIM), C_LIM);
            }
            if (jgo == 3)
                logp_r -= C_LR * (w[6] * (1.0f / 32.0f)
                                  - 2.0f * gam * (w[7] * (1.0f / 32.0f)));
        }
        __syncthreads();  // S7: new Xs visible

        // refresh a0 X-slots (k=17..22 -> j=1..6, quad 2 lanes hold them)
        cur ^= 1;
        if (quad == 2) {
#pragma unroll
            for (int m = 0; m < 4; ++m) {
                const int s = m * 16 + ln15;
                const int sb = (s * 8) ^ XSW(s);
                const f32x4 xv = *(const f32x4*)&Xs[cur][sb];
                const f32x2 xw = *(const f32x2*)&Xs[cur][sb + 4];
                a0[m][1] = (__bf16)xv[0]; a0[m][2] = (__bf16)xv[1];
                a0[m][3] = (__bf16)xv[2]; a0[m][4] = (__bf16)xv[3];
                a0[m][5] = (__bf16)xw[0]; a0[m][6] = (__bf16)xw[1];
            }
        }
    }

    // ---- output: a (B*N, D) then logp (B, N) ----
    for (int e = t; e < 384; e += 256) {
        const int p = e / 6, d = e - p * 6;
        out[(size_t)bb * 384 + e] = Xs[cur][((p * 8) ^ XSW(p)) + d];
    }
    if (jgo == 3) out[(size_t)NB * NP * ND + bb * 64 + qo * 32 + iao] = logp_r;
}

extern "C" void kernel_launch(void* const* d_in, const int* in_sizes, int n_in,
                              void* d_out, int out_size, void* d_ws, size_t ws_size,
                              hipStream_t stream) {
    const float* obs = (const float*)d_in[0];
    const float* a   = (const float*)d_in[1];
    const float* W1  = (const float*)d_in[2];
    const float* b1  = (const float*)d_in[3];
    const float* W2  = (const float*)d_in[4];
    const float* b2  = (const float*)d_in[5];
    const float* W3  = (const float*)d_in[6];
    // d_in[7] = b3: unused (constant offset drops out of grad; q-values never output)
    unsigned short* wsu = (unsigned short*)d_ws;   // needs 286720 bytes
    float* out = (float*)d_out;

    prep_swizzle<<<70, 256, 0, stream>>>(W1, W2, wsu);
    svgd_kernel<<<NB / 2, 256, 0, stream>>>(obs, a, W1, b1, W2, b2, W3, wsu, out);
}

// Round 3
// 675.450 us; speedup vs baseline: 1.0631x; 1.0631x over previous
//
#include <hip/hip_runtime.h>
#include <hip/hip_bf16.h>

#define NB 2048      // batches
#define NP 32        // particles per batch
#define ND 6         // action dim
#define NOBS 17      // obs dim
#define NH 256       // hidden
#define NSTEPS 10
#define C_LR 0.1f
#define C_LIM 1.0f
#define C_LOGNP1 3.4965075614664802f   // float32(log(33))

typedef __bf16 bf16x8 __attribute__((ext_vector_type(8)));
typedef float  f32x4  __attribute__((ext_vector_type(4)));

#define MFMA(a, b, c) __builtin_amdgcn_mfma_f32_16x16x32_bf16(a, b, c, 0, 0, 0)

// fp32 -> bf16 bits, round-to-nearest-even (finite inputs)
static __device__ __forceinline__ unsigned short f2bf(float f) {
    union { float f; unsigned u; } c; c.f = f;
    const unsigned r = c.u + 0x7fffu + ((c.u >> 16) & 1u);
    return (unsigned short)(r >> 16);
}

// packed fp32x2 -> bf16x2 (RNE), 1 VALU op for 2 conversions
static __device__ __forceinline__ unsigned cvtpk_bf16(float lo, float hi) {
    unsigned r;
    asm("v_cvt_pk_bf16_f32 %0, %1, %2" : "=v"(r) : "v"(lo), "v"(hi));
    return r;
}

// A/C column n -> u16 offset base (bits 0-2: n&7, 7-8: (n>>3)&3, 11+: n>>5)
static __device__ __forceinline__ int colpf(int n) {
    return ((n >> 5) << 11) + (((n >> 3) & 3) << 7) + (n & 7);
}

// ---------------------------------------------------------------------------
// Prep: B-fragment-swizzled bf16 copies in d_ws (unchanged).
//   ws[0      ..65535]  : W2    as B (fwd)
//   ws[65536  ..131071] : W2^T  as B (bwd)
//   ws[131072 ..135167] : W1x^T (256x16, cols>=6 zero) as B (score GEMM)
//   ws[135168 ..143359] : W1aug (32x256: rows 0..22 = W1, 23..31 = 0) as B
// ---------------------------------------------------------------------------
__global__ void prep_swizzle(const float* __restrict__ W1, const float* __restrict__ W2,
                             unsigned short* __restrict__ ws) {
    const int g = blockIdx.x * 256 + threadIdx.x;
    unsigned short v[8];
    if (g < 8192) {
        const int l = g & 63, fid = g >> 6;
        const int kt = fid >> 4, nt = fid & 15;
        const int row0 = kt * 32 + (l >> 4) * 8;
        const int col  = nt * 16 + (l & 15);
#pragma unroll
        for (int j = 0; j < 8; ++j) v[j] = f2bf(W2[(row0 + j) * NH + col]);
        ushort4* dst = (ushort4*)(ws + (size_t)g * 8);
        dst[0] = make_ushort4(v[0], v[1], v[2], v[3]);
        dst[1] = make_ushort4(v[4], v[5], v[6], v[7]);
    } else if (g < 16384) {
        const int e = g - 8192;
        const int l = e & 63, fid = e >> 6;
        const int kt = fid >> 4, nt = fid & 15;
        const int row  = nt * 16 + (l & 15);        // W2^T[k][n] = W2[n][k]
        const int col0 = kt * 32 + (l >> 4) * 8;
#pragma unroll
        for (int j = 0; j < 8; ++j) v[j] = f2bf(W2[row * NH + col0 + j]);
        ushort4* dst = (ushort4*)(ws + 65536 + (size_t)e * 8);
        dst[0] = make_ushort4(v[0], v[1], v[2], v[3]);
        dst[1] = make_ushort4(v[4], v[5], v[6], v[7]);
    } else if (g < 16896) {
        const int e = g - 16384;
        const int l = e & 63, kt = e >> 6;
        const int n  = l & 15;
        const int k0 = kt * 32 + (l >> 4) * 8;
#pragma unroll
        for (int j = 0; j < 8; ++j)
            v[j] = (n < ND) ? f2bf(W1[(NOBS + n) * NH + k0 + j]) : (unsigned short)0;
        ushort4* dst = (ushort4*)(ws + 131072 + (size_t)e * 8);
        dst[0] = make_ushort4(v[0], v[1], v[2], v[3]);
        dst[1] = make_ushort4(v[4], v[5], v[6], v[7]);
    } else if (g < 17920) {
        const int e = g - 16896;                    // 16 frags (nt) x 64 lanes
        const int l = e & 63, nt = e >> 6;
        const int col = nt * 16 + (l & 15);
        const int r0  = (l >> 4) * 8;
#pragma unroll
        for (int j = 0; j < 8; ++j)
            v[j] = (r0 + j < NOBS + ND) ? f2bf(W1[(r0 + j) * NH + col]) : (unsigned short)0;
        ushort4* dst = (ushort4*)(ws + 135168 + (size_t)e * 8);
        dst[0] = make_ushort4(v[0], v[1], v[2], v[3]);
        dst[1] = make_ushort4(v[4], v[5], v[6], v[7]);
    }
}

// ---------------------------------------------------------------------------
// Main kernel: one WG per TWO batches (M=64 GEMMs), 256 threads = 4 waves.
// hA layout v2 for 64x256 matrix M[s][c] (u16 addr bits):
//   b0-2 = c&7 | b3-4 = (s>>2)&3 | b5-6 = (s&3), b5 ^= (c>>3)&1 | b7-8 = (c>>3)&3
//   b9-10 = s>>4 | b11+ = c>>5
// Epilogue b16 writes: 2-way banked (was 8-way). ds_read_b128 reads stay
// conflict-free via per-thread base lb (element-verified; R1 passed refcheck).
// phi/median blocks: baseline stride-6/8 scalar LDS reads, fully scalarized
// (no runtime-indexed arrays -> no scratch; R1's vector rewrite spilled).
// ---------------------------------------------------------------------------
__global__ __launch_bounds__(256, 4)
void svgd_kernel(const float* __restrict__ obs, const float* __restrict__ a_in,
                 const float* __restrict__ W1, const float* __restrict__ b1,
                 const float* __restrict__ W2, const float* __restrict__ b2,
                 const float* __restrict__ W3, const unsigned short* __restrict__ ws,
                 float* __restrict__ out)
{
    __shared__ __attribute__((aligned(16))) unsigned short hA[64 * NH]; // 32KB h1 -> dh2 -> masked dh1
    __shared__ float Xs[2][384];        // 3KB double-buffered X, stride 6
    __shared__ float sc_[512];          // 2KB score, stride 8
    __shared__ float med_s[2];
    // total ~37.9KB -> 4 WGs/CU

    const int t    = threadIdx.x;
    const int bb   = blockIdx.x;        // batches 2bb, 2bb+1
    const int lane = t & 63;
    const int wid  = t >> 6;
    const int w4   = wid * 4;           // this wave's first nt (GEMM N-split)
    const int quad = lane >> 4;
    const int ln15 = lane & 15;
    const int qo = t >> 7, iao = (t & 127) >> 2, jgo = t & 3;

    // swizzled hA fragment-read base (replaces lane*8); per-thread constant
    const int lb = (((lane >> 2) & 3) << 3)
                 | (((lane & 3) ^ ((lane >> 4) & 1)) << 5)
                 | ((lane >> 4) << 7);
    // write-side bit5 swizzle mask: ((n>>3)&1)<<5 == ((ln15>>3)&1)<<5 (q-invariant)
    const int x5t = ((ln15 >> 3) & 1) << 5;

    const unsigned short* gW2f = ws;
    const unsigned short* gW2b = ws + 65536;
    const unsigned short* gW1p = ws + 131072;
    const unsigned short* gW1f = ws + 135168;

    // ---- init: obs -> hA scratch (coalesced), X -> Xs[0] ----
    {
        float* scr = (float*)hA;
        const float* obs_g = obs + (size_t)bb * 1088;
        for (int p = t; p < 1088; p += 256) scr[p] = obs_g[p];
        const float* a_g = a_in + (size_t)bb * 384;
        for (int p = t; p < 384; p += 256) Xs[0][p] = a_g[p];
    }
    __syncthreads();
    // a0: A-fragments of [obs|X|0] (64 rows x K=32) in registers, all 4 waves
    bf16x8 a0[4];
    {
        const float* scr = (const float*)hA;
#pragma unroll
        for (int m = 0; m < 4; ++m) {
            const int s = m * 16 + ln15;
#pragma unroll
            for (int j = 0; j < 8; ++j) {
                const int k = quad * 8 + j;
                float v = 0.0f;
                if (k < NOBS) v = scr[s * NOBS + k];
                else if (k < NOBS + ND) v = Xs[0][s * 6 + (k - NOBS)];
                a0[m][j] = (__bf16)v;
            }
        }
    }
    __syncthreads();   // scr reads done before step-0 P0 writes hA

    // ---- persistent per-thread scalars ----
    float b1r[4], b2r[4]; unsigned short w3u[4];
#pragma unroll
    for (int q = 0; q < 4; ++q) {
        const int n = (w4 + q) * 16 + ln15;
        b1r[q] = b1[n]; b2r[q] = b2[n]; w3u[q] = f2bf(W3[n]);
    }

    float logp_r = 0.0f;                // owned by jgo==3 threads
    int cur = 0;
    const f32x4 zv = {0.f, 0.f, 0.f, 0.f};

    for (int step = 0; step < NSTEPS; ++step) {
        // ---- P0: h1 = relu([obs|X] @ W1aug + b1), single pass, mask1 saved ----
        unsigned long long mask1 = 0ull;
        {
            bf16x8 w1B[4];
#pragma unroll
            for (int q = 0; q < 4; ++q)
                w1B[q] = *(const bf16x8*)(gW1f + ((w4 + q) * 64 + lane) * 8);
            f32x4 acc0[4][4];
#pragma unroll
            for (int m = 0; m < 4; ++m)
#pragma unroll
                for (int q = 0; q < 4; ++q) acc0[m][q] = MFMA(a0[m], w1B[q], zv);
#pragma unroll
            for (int q = 0; q < 4; ++q) {
                const int cq = colpf((w4 + q) * 16 + ln15) + quad * 8;
                const int ax0 = (cq     ) ^ x5t;
                const int ax1 = (cq + 32) ^ x5t;
                const int ax2 = (cq + 64) ^ x5t;
                const int ax3 = (cq + 96) ^ x5t;
                const float b1v = b1r[q];
#pragma unroll
                for (int m = 0; m < 4; ++m) {
                    const float f0 = acc0[m][q][0] + b1v;
                    const float f1 = acc0[m][q][1] + b1v;
                    const float f2 = acc0[m][q][2] + b1v;
                    const float f3 = acc0[m][q][3] + b1v;
                    if (f0 > 0.f) mask1 |= 1ull << (q * 16 + m * 4 + 0);
                    if (f1 > 0.f) mask1 |= 1ull << (q * 16 + m * 4 + 1);
                    if (f2 > 0.f) mask1 |= 1ull << (q * 16 + m * 4 + 2);
                    if (f3 > 0.f) mask1 |= 1ull << (q * 16 + m * 4 + 3);
                    const unsigned pk01 = cvtpk_bf16(fmaxf(f0, 0.f), fmaxf(f1, 0.f));
                    const unsigned pk23 = cvtpk_bf16(fmaxf(f2, 0.f), fmaxf(f3, 0.f));
                    hA[ax0 + m * 512] = (unsigned short)pk01;
                    hA[ax1 + m * 512] = (unsigned short)(pk01 >> 16);
                    hA[ax2 + m * 512] = (unsigned short)pk23;
                    hA[ax3 + m * 512] = (unsigned short)(pk23 >> 16);
                }
            }
        }
        __syncthreads();  // S1

        // ---- P2: fwd GEMM h2_pre = h1 @ W2, single pass ----
        {
            f32x4 acc[4][4];
#pragma unroll
            for (int m = 0; m < 4; ++m)
#pragma unroll
                for (int q = 0; q < 4; ++q) acc[m][q] = zv;
#pragma unroll 2
            for (int kt = 0; kt < 8; ++kt) {
                bf16x8 a[4];
#pragma unroll
                for (int m = 0; m < 4; ++m)
                    a[m] = *(const bf16x8*)&hA[(kt * 4 + m) * 512 + lb];
#pragma unroll
                for (int q = 0; q < 4; ++q) {
                    const bf16x8 bf = *(const bf16x8*)(gW2f + ((kt * 16 + w4 + q) * 64 + lane) * 8);
#pragma unroll
                    for (int m = 0; m < 4; ++m) acc[m][q] = MFMA(a[m], bf, acc[m][q]);
                }
            }
            __syncthreads();  // S2: all h1 reads done
            // epilogue: dh2 = (h2_pre + b2 > 0) ? W3 : 0, straight from acc
#pragma unroll
            for (int q = 0; q < 4; ++q) {
                const int cq = colpf((w4 + q) * 16 + ln15) + quad * 8;
                const int ax0 = (cq     ) ^ x5t;
                const int ax1 = (cq + 32) ^ x5t;
                const int ax2 = (cq + 64) ^ x5t;
                const int ax3 = (cq + 96) ^ x5t;
                const float b2v = b2r[q];
                const unsigned short w3v = w3u[q];
#pragma unroll
                for (int m = 0; m < 4; ++m) {
                    hA[ax0 + m * 512] = (acc[m][q][0] + b2v > 0.f) ? w3v : (unsigned short)0;
                    hA[ax1 + m * 512] = (acc[m][q][1] + b2v > 0.f) ? w3v : (unsigned short)0;
                    hA[ax2 + m * 512] = (acc[m][q][2] + b2v > 0.f) ? w3v : (unsigned short)0;
                    hA[ax3 + m * 512] = (acc[m][q][3] + b2v > 0.f) ? w3v : (unsigned short)0;
                }
            }
        }
        __syncthreads();  // S3: dh2 visible

        // ---- P3: bwd GEMM dh1 = dh2 @ W2^T, single pass ----
        {
            f32x4 acc2[4][4];
#pragma unroll
            for (int m = 0; m < 4; ++m)
#pragma unroll
                for (int q = 0; q < 4; ++q) acc2[m][q] = zv;
#pragma unroll 2
            for (int kt = 0; kt < 8; ++kt) {
                bf16x8 a[4];
#pragma unroll
                for (int m = 0; m < 4; ++m)
                    a[m] = *(const bf16x8*)&hA[(kt * 4 + m) * 512 + lb];
#pragma unroll
                for (int q = 0; q < 4; ++q) {
                    const bf16x8 bf = *(const bf16x8*)(gW2b + ((kt * 16 + w4 + q) * 64 + lane) * 8);
#pragma unroll
                    for (int m = 0; m < 4; ++m) acc2[m][q] = MFMA(a[m], bf, acc2[m][q]);
                }
            }
            __syncthreads();  // S4: all dh2 reads done
            // epilogue: masked dh1 from register bitmask
#pragma unroll
            for (int q = 0; q < 4; ++q) {
                const int cq = colpf((w4 + q) * 16 + ln15) + quad * 8;
                const int ax0 = (cq     ) ^ x5t;
                const int ax1 = (cq + 32) ^ x5t;
                const int ax2 = (cq + 64) ^ x5t;
                const int ax3 = (cq + 96) ^ x5t;
#pragma unroll
                for (int m = 0; m < 4; ++m) {
                    const int kb = q * 16 + m * 4;
                    const float v0 = ((mask1 >> (kb + 0)) & 1ull) ? acc2[m][q][0] : 0.f;
                    const float v1 = ((mask1 >> (kb + 1)) & 1ull) ? acc2[m][q][1] : 0.f;
                    const float v2 = ((mask1 >> (kb + 2)) & 1ull) ? acc2[m][q][2] : 0.f;
                    const float v3 = ((mask1 >> (kb + 3)) & 1ull) ? acc2[m][q][3] : 0.f;
                    const unsigned pk01 = cvtpk_bf16(v0, v1);
                    const unsigned pk23 = cvtpk_bf16(v2, v3);
                    hA[ax0 + m * 512] = (unsigned short)pk01;
                    hA[ax1 + m * 512] = (unsigned short)(pk01 >> 16);
                    hA[ax2 + m * 512] = (unsigned short)pk23;
                    hA[ax3 + m * 512] = (unsigned short)(pk23 >> 16);
                }
            }
        }
        __syncthreads();  // S5: masked dh1 visible

        // ---- P5: waves 2,3: score GEMM; waves 0,1: exact median ----
        if (wid >= 2) {
            const int mb = (wid - 2) * 2;
            f32x4 sa[2] = {zv, zv};
#pragma unroll
            for (int kt = 0; kt < 8; ++kt) {
                const bf16x8 bw = *(const bf16x8*)(gW1p + (kt * 64 + lane) * 8);
#pragma unroll
                for (int mm = 0; mm < 2; ++mm) {
                    const bf16x8 a = *(const bf16x8*)&hA[(kt * 4 + mb + mm) * 512 + lb];
                    sa[mm] = MFMA(a, bw, sa[mm]);
                }
            }
            if (ln15 < ND) {
#pragma unroll
                for (int mm = 0; mm < 2; ++mm)
#pragma unroll
                    for (int reg = 0; reg < 4; ++reg)
                        sc_[((mb + mm) * 16 + quad * 4 + reg) * 8 + ln15] = sa[mm][reg];
            }
        } else {
            // rank-239 of 496 pair dists == rank-511 of full 1024 multiset.
            // Bits 30..8 suffice: med rel-err < 2^-15, invisible vs bf16 noise.
            const float* Xc = &Xs[cur][wid * 192];
            unsigned u[8];
#pragma unroll
            for (int r = 0; r < 8; ++r) {
                const int e = lane + 64 * r;
                if (e < 496) {
                    int i = (int)((63.0f - sqrtf(3969.0f - 8.0f * (float)e)) * 0.5f);
                    while (i * (63 - i) / 2 > e) --i;
                    while ((i + 1) * (62 - i) / 2 <= e) ++i;
                    const int j = i + 1 + (e - i * (63 - i) / 2);
                    float s = 0.f;
#pragma unroll
                    for (int d = 0; d < ND; ++d) {
                        const float df = Xc[i * 6 + d] - Xc[j * 6 + d];
                        s += df * df;
                    }
                    u[r] = __float_as_uint(s);
                } else u[r] = 0x7f800000u;
            }
            unsigned P = 0u;
            for (int bit = 30; bit >= 8; --bit) {
                const unsigned Q = P | (1u << bit);
                int c = 0;
#pragma unroll
                for (int r = 0; r < 8; ++r)
                    c += __popcll(__ballot(u[r] < Q));
                if (c <= 239) P = Q;
            }
            if (lane == 0) med_s[wid] = __uint_as_float(P);
        }
        __syncthreads();  // S6

        // ---- phi/l4/l5 partials; thread (batch qo, particle iao, 8 j's) ----
        // Fully scalarized: named scalars only, select trees for the two
        // runtime-indexed picks (no arrays -> no scratch spill).
        {
            const int nxt = cur ^ 1;
            const float gam = 1.0f / (1e-8f + med_s[qo] / C_LOGNP1);
            const float* Xc = &Xs[cur][qo * 192];
            const float xi0 = Xc[iao * 6 + 0], xi1 = Xc[iao * 6 + 1];
            const float xi2 = Xc[iao * 6 + 2], xi3 = Xc[iao * 6 + 3];
            const float xi4 = Xc[iao * 6 + 4], xi5 = Xc[iao * 6 + 5];
            float w0 = 0.f, w1 = 0.f, w2 = 0.f, w3 = 0.f;
            float w4_ = 0.f, w5 = 0.f, w6 = 0.f, w7 = 0.f;
#pragma unroll
            for (int jj = 0; jj < 8; ++jj) {
                const int j = jgo * 8 + jj;
                const float d0 = xi0 - Xc[j * 6 + 0];
                const float d1 = xi1 - Xc[j * 6 + 1];
                const float d2 = xi2 - Xc[j * 6 + 2];
                const float d3 = xi3 - Xc[j * 6 + 3];
                const float d4 = xi4 - Xc[j * 6 + 4];
                const float d5 = xi5 - Xc[j * 6 + 5];
                const float s0 = sc_[(qo * 32 + j) * 8 + 0];
                const float s1 = sc_[(qo * 32 + j) * 8 + 1];
                const float s2 = sc_[(qo * 32 + j) * 8 + 2];
                const float s3 = sc_[(qo * 32 + j) * 8 + 3];
                const float s4 = sc_[(qo * 32 + j) * 8 + 4];
                const float s5 = sc_[(qo * 32 + j) * 8 + 5];
                const float dsv = d0 * d0 + d1 * d1 + d2 * d2 + d3 * d3 + d4 * d4 + d5 * d5;
                const float dot = d0 * s0 + d1 * s1 + d2 * s2 + d3 * s3 + d4 * s4 + d5 * s5;
                const float kap = __expf(-gam * dsv);
                const float tg = 2.0f * gam * kap;
                w0 += kap * s0 + tg * d0;
                w1 += kap * s1 + tg * d1;
                w2 += kap * s2 + tg * d2;
                w3 += kap * s3 + tg * d3;
                w4_ += kap * s4 + tg * d4;
                w5 += kap * s5 + tg * d5;
                w6 -= tg * dot;                 // line_4 partial
                w7 += tg * dsv - 6.0f * kap;    // line_5 partial (pre -2*gamma)
            }
#pragma unroll
            for (int off = 1; off < 4; off <<= 1) {
                w0 += __shfl_xor(w0, off);  w1 += __shfl_xor(w1, off);
                w2 += __shfl_xor(w2, off);  w3 += __shfl_xor(w3, off);
                w4_ += __shfl_xor(w4_, off); w5 += __shfl_xor(w5, off);
                w6 += __shfl_xor(w6, off);  w7 += __shfl_xor(w7, off);
            }
            // commit to Xs[nxt] (disjoint buffer: no barrier vs phi reads)
            const int base = (qo * 32 + iao) * 6;
            {
                const float xs = (jgo == 0) ? xi0 : (jgo == 1) ? xi1 : (jgo == 2) ? xi2 : xi3;
                const float wsv = (jgo == 0) ? w0 : (jgo == 1) ? w1 : (jgo == 2) ? w2 : w3;
                const float x = xs + C_LR * (wsv * (1.0f / 32.0f));
                Xs[nxt][base + jgo] = fminf(fmaxf(x, -C_LIM), C_LIM);
            }
            if (jgo < 2) {
                const float xs = (jgo == 0) ? xi4 : xi5;
                const float wsv = (jgo == 0) ? w4_ : w5;
                const float x = xs + C_LR * (wsv * (1.0f / 32.0f));
                Xs[nxt][base + jgo + 4] = fminf(fmaxf(x, -C_LIM), C_LIM);
            }
            if (jgo == 3)
                logp_r -= C_LR * (w6 * (1.0f / 32.0f)
                                  - 2.0f * gam * (w7 * (1.0f / 32.0f)));
        }
        __syncthreads();  // S7: new Xs visible

        // refresh a0 X-slots (k=17..22 -> j=1..6, quad 2 lanes hold them)
        cur ^= 1;
        if (quad == 2) {
#pragma unroll
            for (int m = 0; m < 4; ++m) {
                const int s = m * 16 + ln15;
#pragma unroll
                for (int j = 1; j <= 6; ++j)
                    a0[m][j] = (__bf16)Xs[cur][s * 6 + (j - 1)];
            }
        }
    }

    // ---- output: a (B*N, D) then logp (B, N) ----
    for (int p = t; p < 384; p += 256) out[(size_t)bb * 384 + p] = Xs[cur][p];
    if (jgo == 3) out[(size_t)NB * NP * ND + bb * 64 + qo * 32 + iao] = logp_r;
}

extern "C" void kernel_launch(void* const* d_in, const int* in_sizes, int n_in,
                              void* d_out, int out_size, void* d_ws, size_t ws_size,
                              hipStream_t stream) {
    const float* obs = (const float*)d_in[0];
    const float* a   = (const float*)d_in[1];
    const float* W1  = (const float*)d_in[2];
    const float* b1  = (const float*)d_in[3];
    const float* W2  = (const float*)d_in[4];
    const float* b2  = (const float*)d_in[5];
    const float* W3  = (const float*)d_in[6];
    // d_in[7] = b3: unused (constant offset drops out of grad; q-values never output)
    unsigned short* wsu = (unsigned short*)d_ws;   // needs 286720 bytes
    float* out = (float*)d_out;

    prep_swizzle<<<70, 256, 0, stream>>>(W1, W2, wsu);
    svgd_kernel<<<NB / 2, 256, 0, stream>>>(obs, a, W1, b1, W2, b2, W3, wsu, out);
}

// Round 4
// 489.834 us; speedup vs baseline: 1.4660x; 1.3789x over previous
//
#include <hip/hip_runtime.h>
#include <hip/hip_bf16.h>

#define NB 2048      // batches
#define NP 32        // particles per batch
#define ND 6         // action dim
#define NOBS 17      // obs dim
#define NH 256       // hidden
#define NSTEPS 10
#define C_LR 0.1f
#define C_LIM 1.0f
#define C_LOGNP1 3.4965075614664802f   // float32(log(33))

typedef __bf16 bf16x8 __attribute__((ext_vector_type(8)));
typedef float  f32x4  __attribute__((ext_vector_type(4)));

#define MFMA(a, b, c) __builtin_amdgcn_mfma_f32_16x16x32_bf16(a, b, c, 0, 0, 0)

// fp32 -> bf16 bits, round-to-nearest-even (finite inputs)
static __device__ __forceinline__ unsigned short f2bf(float f) {
    union { float f; unsigned u; } c; c.f = f;
    const unsigned r = c.u + 0x7fffu + ((c.u >> 16) & 1u);
    return (unsigned short)(r >> 16);
}

// A/C column n -> u16 offset base within a 64-row A-layout LDS tile
static __device__ __forceinline__ int colpf(int n) {
    return ((n >> 5) << 11) + (((n >> 3) & 3) << 7) + (n & 7);
}

// ---------------------------------------------------------------------------
// Prep: B-fragment-swizzled bf16 copies in d_ws (unchanged).
//   ws[0      ..65535]  : W2    as B (fwd)
//   ws[65536  ..131071] : W2^T  as B (bwd)
//   ws[131072 ..135167] : W1x^T (256x16, cols>=6 zero) as B (score GEMM)
//   ws[135168 ..143359] : W1aug (32x256: rows 0..22 = W1, 23..31 = 0) as B
// ---------------------------------------------------------------------------
__global__ void prep_swizzle(const float* __restrict__ W1, const float* __restrict__ W2,
                             unsigned short* __restrict__ ws) {
    const int g = blockIdx.x * 256 + threadIdx.x;
    unsigned short v[8];
    if (g < 8192) {
        const int l = g & 63, fid = g >> 6;
        const int kt = fid >> 4, nt = fid & 15;
        const int row0 = kt * 32 + (l >> 4) * 8;
        const int col  = nt * 16 + (l & 15);
#pragma unroll
        for (int j = 0; j < 8; ++j) v[j] = f2bf(W2[(row0 + j) * NH + col]);
        ushort4* dst = (ushort4*)(ws + (size_t)g * 8);
        dst[0] = make_ushort4(v[0], v[1], v[2], v[3]);
        dst[1] = make_ushort4(v[4], v[5], v[6], v[7]);
    } else if (g < 16384) {
        const int e = g - 8192;
        const int l = e & 63, fid = e >> 6;
        const int kt = fid >> 4, nt = fid & 15;
        const int row  = nt * 16 + (l & 15);        // W2^T[k][n] = W2[n][k]
        const int col0 = kt * 32 + (l >> 4) * 8;
#pragma unroll
        for (int j = 0; j < 8; ++j) v[j] = f2bf(W2[row * NH + col0 + j]);
        ushort4* dst = (ushort4*)(ws + 65536 + (size_t)e * 8);
        dst[0] = make_ushort4(v[0], v[1], v[2], v[3]);
        dst[1] = make_ushort4(v[4], v[5], v[6], v[7]);
    } else if (g < 16896) {
        const int e = g - 16384;
        const int l = e & 63, kt = e >> 6;
        const int n  = l & 15;
        const int k0 = kt * 32 + (l >> 4) * 8;
#pragma unroll
        for (int j = 0; j < 8; ++j)
            v[j] = (n < ND) ? f2bf(W1[(NOBS + n) * NH + k0 + j]) : (unsigned short)0;
        ushort4* dst = (ushort4*)(ws + 131072 + (size_t)e * 8);
        dst[0] = make_ushort4(v[0], v[1], v[2], v[3]);
        dst[1] = make_ushort4(v[4], v[5], v[6], v[7]);
    } else if (g < 17920) {
        const int e = g - 16896;                    // 16 frags (nt) x 64 lanes
        const int l = e & 63, nt = e >> 6;
        const int col = nt * 16 + (l & 15);
        const int r0  = (l >> 4) * 8;
#pragma unroll
        for (int j = 0; j < 8; ++j)
            v[j] = (r0 + j < NOBS + ND) ? f2bf(W1[(r0 + j) * NH + col]) : (unsigned short)0;
        ushort4* dst = (ushort4*)(ws + 135168 + (size_t)e * 8);
        dst[0] = make_ushort4(v[0], v[1], v[2], v[3]);
        dst[1] = make_ushort4(v[4], v[5], v[6], v[7]);
    }
}

// ---------------------------------------------------------------------------
// Main kernel: one WG per TWO batches (M=64 GEMMs), 256 threads = 4 waves.
// A-fragment LDS layout for 64x256 matrix M[s][c] (R0 original):
//   fid = (c>>5)*4 + (s>>4); addr(u16) = fid*512 + (((c>>3)&3)*16 + (s&15))*8 + (c&7)
// Single N-pass GEMMs: 4 nt/wave, 64 AGPR accumulators, one A-sweep per GEMM.
// R3 delta vs R0 baseline: phi block fully scalarized (no runtime-indexed
// private arrays -> no scratch spill; baseline's xi[jgo]/w[jgo] were demoted
// to scratch = the 160MB WRITE / 418MB FETCH excess), median bits 30..8.
// Epilogues/layout deliberately byte-identical to R0 (R1/R2's restructured
// epilogues tipped the 128-reg budget -> 0.5GB spill traffic).
// ---------------------------------------------------------------------------
__global__ __launch_bounds__(256, 4)
void svgd_kernel(const float* __restrict__ obs, const float* __restrict__ a_in,
                 const float* __restrict__ W1, const float* __restrict__ b1,
                 const float* __restrict__ W2, const float* __restrict__ b2,
                 const float* __restrict__ W3, const unsigned short* __restrict__ ws,
                 float* __restrict__ out)
{
    __shared__ __attribute__((aligned(16))) unsigned short hA[64 * NH]; // 32KB h1 -> dh2 -> masked dh1
    __shared__ float Xs[2][384];        // 3KB double-buffered X, stride 6
    __shared__ float sc_[512];          // 2KB score, stride 8
    __shared__ float med_s[2];
    // total ~37.9KB -> 4 WGs/CU

    const int t    = threadIdx.x;
    const int bb   = blockIdx.x;        // batches 2bb, 2bb+1
    const int lane = t & 63;
    const int wid  = t >> 6;
    const int w4   = wid * 4;           // this wave's first nt (GEMM N-split)
    const int quad = lane >> 4;
    const int ln15 = lane & 15;
    const int qo = t >> 7, iao = (t & 127) >> 2, jgo = t & 3;

    const unsigned short* gW2f = ws;
    const unsigned short* gW2b = ws + 65536;
    const unsigned short* gW1p = ws + 131072;
    const unsigned short* gW1f = ws + 135168;

    // ---- init: obs -> hA scratch (coalesced), X -> Xs[0] ----
    {
        float* scr = (float*)hA;
        const float* obs_g = obs + (size_t)bb * 1088;
        for (int p = t; p < 1088; p += 256) scr[p] = obs_g[p];
        const float* a_g = a_in + (size_t)bb * 384;
        for (int p = t; p < 384; p += 256) Xs[0][p] = a_g[p];
    }
    __syncthreads();
    // a0: A-fragments of [obs|X|0] (64 rows x K=32) in registers, all 4 waves
    bf16x8 a0[4];
    {
        const float* scr = (const float*)hA;
#pragma unroll
        for (int m = 0; m < 4; ++m) {
            const int s = m * 16 + ln15;
#pragma unroll
            for (int j = 0; j < 8; ++j) {
                const int k = quad * 8 + j;
                float v = 0.0f;
                if (k < NOBS) v = scr[s * NOBS + k];
                else if (k < NOBS + ND) v = Xs[0][s * 6 + (k - NOBS)];
                a0[m][j] = (__bf16)v;
            }
        }
    }
    __syncthreads();   // scr reads done before step-0 P0 writes hA

    // ---- persistent per-thread scalars (no w1b: re-read from L2 each step) ----
    float b1r[4], b2r[4]; unsigned short w3u[4];
#pragma unroll
    for (int q = 0; q < 4; ++q) {
        const int n = (w4 + q) * 16 + ln15;
        b1r[q] = b1[n]; b2r[q] = b2[n]; w3u[q] = f2bf(W3[n]);
    }

    float logp_r = 0.0f;                // owned by jgo==3 threads
    int cur = 0;
    const f32x4 zv = {0.f, 0.f, 0.f, 0.f};

    for (int step = 0; step < NSTEPS; ++step) {
        // ---- P0: h1 = relu([obs|X] @ W1aug + b1), single pass, mask1 saved ----
        unsigned long long mask1 = 0ull;
        {
            bf16x8 w1B[4];
#pragma unroll
            for (int q = 0; q < 4; ++q)
                w1B[q] = *(const bf16x8*)(gW1f + ((w4 + q) * 64 + lane) * 8);
            f32x4 acc0[4][4];
#pragma unroll
            for (int m = 0; m < 4; ++m)
#pragma unroll
                for (int q = 0; q < 4; ++q) acc0[m][q] = MFMA(a0[m], w1B[q], zv);
#pragma unroll
            for (int q = 0; q < 4; ++q) {
                const int cp = colpf((w4 + q) * 16 + ln15);
#pragma unroll
                for (int m = 0; m < 4; ++m)
#pragma unroll
                    for (int reg = 0; reg < 4; ++reg) {
                        const float hv = acc0[m][q][reg] + b1r[q];
                        const int idx = cp + m * 512 + (quad * 4 + reg) * 8;
                        if (hv > 0.f) {
                            mask1 |= 1ull << (q * 16 + m * 4 + reg);
                            hA[idx] = f2bf(hv);
                        } else hA[idx] = 0;
                    }
            }
        }
        __syncthreads();  // S1

        // ---- P2: fwd GEMM h2_pre = h1 @ W2, single pass ----
        {
            f32x4 acc[4][4];
#pragma unroll
            for (int m = 0; m < 4; ++m)
#pragma unroll
                for (int q = 0; q < 4; ++q) acc[m][q] = zv;
#pragma unroll 2
            for (int kt = 0; kt < 8; ++kt) {
                bf16x8 a[4];
#pragma unroll
                for (int m = 0; m < 4; ++m)
                    a[m] = *(const bf16x8*)&hA[(kt * 4 + m) * 512 + lane * 8];
#pragma unroll
                for (int q = 0; q < 4; ++q) {
                    const bf16x8 bf = *(const bf16x8*)(gW2f + ((kt * 16 + w4 + q) * 64 + lane) * 8);
#pragma unroll
                    for (int m = 0; m < 4; ++m) acc[m][q] = MFMA(a[m], bf, acc[m][q]);
                }
            }
            __syncthreads();  // S2: all h1 reads done
            // epilogue: dh2 = (h2_pre + b2 > 0) ? W3 : 0, straight from acc
#pragma unroll
            for (int q = 0; q < 4; ++q) {
                const int cp = colpf((w4 + q) * 16 + ln15);
                const float b2v = b2r[q];
                const unsigned short w3v = w3u[q];
#pragma unroll
                for (int m = 0; m < 4; ++m)
#pragma unroll
                    for (int reg = 0; reg < 4; ++reg) {
                        const int idx = cp + m * 512 + (quad * 4 + reg) * 8;
                        hA[idx] = (acc[m][q][reg] + b2v > 0.f) ? w3v : (unsigned short)0;
                    }
            }
        }
        __syncthreads();  // S3: dh2 visible

        // ---- P3: bwd GEMM dh1 = dh2 @ W2^T, single pass ----
        {
            f32x4 acc2[4][4];
#pragma unroll
            for (int m = 0; m < 4; ++m)
#pragma unroll
                for (int q = 0; q < 4; ++q) acc2[m][q] = zv;
#pragma unroll 2
            for (int kt = 0; kt < 8; ++kt) {
                bf16x8 a[4];
#pragma unroll
                for (int m = 0; m < 4; ++m)
                    a[m] = *(const bf16x8*)&hA[(kt * 4 + m) * 512 + lane * 8];
#pragma unroll
                for (int q = 0; q < 4; ++q) {
                    const bf16x8 bf = *(const bf16x8*)(gW2b + ((kt * 16 + w4 + q) * 64 + lane) * 8);
#pragma unroll
                    for (int m = 0; m < 4; ++m) acc2[m][q] = MFMA(a[m], bf, acc2[m][q]);
                }
            }
            __syncthreads();  // S4: all dh2 reads done
            // epilogue: masked dh1 from register bitmask
#pragma unroll
            for (int q = 0; q < 4; ++q) {
                const int cp = colpf((w4 + q) * 16 + ln15);
#pragma unroll
                for (int m = 0; m < 4; ++m)
#pragma unroll
                    for (int reg = 0; reg < 4; ++reg) {
                        const int idx = cp + m * 512 + (quad * 4 + reg) * 8;
                        hA[idx] = ((mask1 >> (q * 16 + m * 4 + reg)) & 1ull)
                                      ? f2bf(acc2[m][q][reg]) : (unsigned short)0;
                    }
            }
        }
        __syncthreads();  // S5: masked dh1 visible

        // ---- P5: waves 2,3: score GEMM; waves 0,1: exact median ----
        if (wid >= 2) {
            const int mb = (wid - 2) * 2;
            f32x4 sa[2] = {zv, zv};
#pragma unroll
            for (int kt = 0; kt < 8; ++kt) {
                const bf16x8 bw = *(const bf16x8*)(gW1p + (kt * 64 + lane) * 8);
#pragma unroll
                for (int mm = 0; mm < 2; ++mm) {
                    const bf16x8 a = *(const bf16x8*)&hA[(kt * 4 + mb + mm) * 512 + lane * 8];
                    sa[mm] = MFMA(a, bw, sa[mm]);
                }
            }
            if (ln15 < ND) {
#pragma unroll
                for (int mm = 0; mm < 2; ++mm)
#pragma unroll
                    for (int reg = 0; reg < 4; ++reg)
                        sc_[((mb + mm) * 16 + quad * 4 + reg) * 8 + ln15] = sa[mm][reg];
            }
        } else {
            // rank-239 of 496 pair dists == rank-511 of full 1024 multiset.
            // Bits 30..8 suffice: med rel-err < 2^-15, invisible vs bf16 noise.
            const float* Xc = &Xs[cur][wid * 192];
            unsigned u[8];
#pragma unroll
            for (int r = 0; r < 8; ++r) {
                const int e = lane + 64 * r;
                if (e < 496) {
                    int i = (int)((63.0f - sqrtf(3969.0f - 8.0f * (float)e)) * 0.5f);
                    while (i * (63 - i) / 2 > e) --i;
                    while ((i + 1) * (62 - i) / 2 <= e) ++i;
                    const int j = i + 1 + (e - i * (63 - i) / 2);
                    float s = 0.f;
#pragma unroll
                    for (int d = 0; d < ND; ++d) {
                        const float df = Xc[i * 6 + d] - Xc[j * 6 + d];
                        s += df * df;
                    }
                    u[r] = __float_as_uint(s);
                } else u[r] = 0x7f800000u;
            }
            unsigned P = 0u;
            for (int bit = 30; bit >= 8; --bit) {
                const unsigned Q = P | (1u << bit);
                int c = 0;
#pragma unroll
                for (int r = 0; r < 8; ++r)
                    c += __popcll(__ballot(u[r] < Q));
                if (c <= 239) P = Q;
            }
            if (lane == 0) med_s[wid] = __uint_as_float(P);
        }
        __syncthreads();  // S6

        // ---- phi/l4/l5 partials; thread (batch qo, particle iao, 8 j's) ----
        // Fully scalarized: named scalars only, select trees for the
        // runtime-indexed picks (no private arrays -> no scratch spill).
        {
            const int nxt = cur ^ 1;
            const float gam = 1.0f / (1e-8f + med_s[qo] / C_LOGNP1);
            const float* Xc = &Xs[cur][qo * 192];
            const float xi0 = Xc[iao * 6 + 0], xi1 = Xc[iao * 6 + 1];
            const float xi2 = Xc[iao * 6 + 2], xi3 = Xc[iao * 6 + 3];
            const float xi4 = Xc[iao * 6 + 4], xi5 = Xc[iao * 6 + 5];
            float w0 = 0.f, w1 = 0.f, w2 = 0.f, w3 = 0.f;
            float w4_ = 0.f, w5 = 0.f, w6 = 0.f, w7 = 0.f;
#pragma unroll
            for (int jj = 0; jj < 8; ++jj) {
                const int j = jgo * 8 + jj;
                const float d0 = xi0 - Xc[j * 6 + 0];
                const float d1 = xi1 - Xc[j * 6 + 1];
                const float d2 = xi2 - Xc[j * 6 + 2];
                const float d3 = xi3 - Xc[j * 6 + 3];
                const float d4 = xi4 - Xc[j * 6 + 4];
                const float d5 = xi5 - Xc[j * 6 + 5];
                const float s0 = sc_[(qo * 32 + j) * 8 + 0];
                const float s1 = sc_[(qo * 32 + j) * 8 + 1];
                const float s2 = sc_[(qo * 32 + j) * 8 + 2];
                const float s3 = sc_[(qo * 32 + j) * 8 + 3];
                const float s4 = sc_[(qo * 32 + j) * 8 + 4];
                const float s5 = sc_[(qo * 32 + j) * 8 + 5];
                const float dsv = d0 * d0 + d1 * d1 + d2 * d2 + d3 * d3 + d4 * d4 + d5 * d5;
                const float dot = d0 * s0 + d1 * s1 + d2 * s2 + d3 * s3 + d4 * s4 + d5 * s5;
                const float kap = __expf(-gam * dsv);
                const float tg = 2.0f * gam * kap;
                w0 += kap * s0 + tg * d0;
                w1 += kap * s1 + tg * d1;
                w2 += kap * s2 + tg * d2;
                w3 += kap * s3 + tg * d3;
                w4_ += kap * s4 + tg * d4;
                w5 += kap * s5 + tg * d5;
                w6 -= tg * dot;                 // line_4 partial
                w7 += tg * dsv - 6.0f * kap;    // line_5 partial (pre -2*gamma)
            }
#pragma unroll
            for (int off = 1; off < 4; off <<= 1) {
                w0 += __shfl_xor(w0, off);  w1 += __shfl_xor(w1, off);
                w2 += __shfl_xor(w2, off);  w3 += __shfl_xor(w3, off);
                w4_ += __shfl_xor(w4_, off); w5 += __shfl_xor(w5, off);
                w6 += __shfl_xor(w6, off);  w7 += __shfl_xor(w7, off);
            }
            // commit to Xs[nxt] (disjoint buffer: no barrier vs phi reads)
            const int base = (qo * 32 + iao) * 6;
            {
                const float xs = (jgo == 0) ? xi0 : (jgo == 1) ? xi1 : (jgo == 2) ? xi2 : xi3;
                const float wsv = (jgo == 0) ? w0 : (jgo == 1) ? w1 : (jgo == 2) ? w2 : w3;
                const float x = xs + C_LR * (wsv * (1.0f / 32.0f));
                Xs[nxt][base + jgo] = fminf(fmaxf(x, -C_LIM), C_LIM);
            }
            if (jgo < 2) {
                const float xs = (jgo == 0) ? xi4 : xi5;
                const float wsv = (jgo == 0) ? w4_ : w5;
                const float x = xs + C_LR * (wsv * (1.0f / 32.0f));
                Xs[nxt][base + jgo + 4] = fminf(fmaxf(x, -C_LIM), C_LIM);
            }
            if (jgo == 3)
                logp_r -= C_LR * (w6 * (1.0f / 32.0f)
                                  - 2.0f * gam * (w7 * (1.0f / 32.0f)));
        }
        __syncthreads();  // S7: new Xs visible

        // refresh a0 X-slots (k=17..22 -> j=1..6, quad 2 lanes hold them)
        cur ^= 1;
        if (quad == 2) {
#pragma unroll
            for (int m = 0; m < 4; ++m) {
                const int s = m * 16 + ln15;
#pragma unroll
                for (int j = 1; j <= 6; ++j)
                    a0[m][j] = (__bf16)Xs[cur][s * 6 + (j - 1)];
            }
        }
    }

    // ---- output: a (B*N, D) then logp (B, N) ----
    for (int p = t; p < 384; p += 256) out[(size_t)bb * 384 + p] = Xs[cur][p];
    if (jgo == 3) out[(size_t)NB * NP * ND + bb * 64 + qo * 32 + iao] = logp_r;
}

extern "C" void kernel_launch(void* const* d_in, const int* in_sizes, int n_in,
                              void* d_out, int out_size, void* d_ws, size_t ws_size,
                              hipStream_t stream) {
    const float* obs = (const float*)d_in[0];
    const float* a   = (const float*)d_in[1];
    const float* W1  = (const float*)d_in[2];
    const float* b1  = (const float*)d_in[3];
    const float* W2  = (const float*)d_in[4];
    const float* b2  = (const float*)d_in[5];
    const float* W3  = (const float*)d_in[6];
    // d_in[7] = b3: unused (constant offset drops out of grad; q-values never output)
    unsigned short* wsu = (unsigned short*)d_ws;   // needs 286720 bytes
    float* out = (float*)d_out;

    prep_swizzle<<<70, 256, 0, stream>>>(W1, W2, wsu);
    svgd_kernel<<<NB / 2, 256, 0, stream>>>(obs, a, W1, b1, W2, b2, W3, wsu, out);
}